// Round 4
// baseline (343.332 us; speedup 1.0000x reference)
//
#include <hip/hip_runtime.h>

// Problem constants (fixed by setup_inputs)
#define N_IMG 4
#define E_DIM 16
#define H_DIM 768
#define W_DIM 768
#define P_PIX (H_DIM * W_DIM)   // 589824 pixels per image
#define C_CL 32

#define DELTA_VAR 0.5f
#define DELTA_DIST 2.0f
#define GAMMA_W 0.001f
#define EPS_F 1e-12f

// Workspace layout (floats):
//   [0,    2048): sums   [N][C][E]
//   [2048, 2176): counts [N][C]
//   [2176, 2180): varsum [N]
#define WS_SUMS 0
#define WS_CNT 2048
#define WS_VAR 2176
#define WS_TOTAL 2180

// Smaller tiles -> 2304 blocks/pass -> 9216 waves (oversubscribes 8192 cap).
#define PX1 1024
#define BX1 (P_PIX / PX1)   // 576
#define STEPS1 16           // 256 px per wave, 16 px per MFMA step
#define PX2 1024
#define BX2 (P_PIX / PX2)   // 576

typedef __attribute__((ext_vector_type(8))) short short8;
typedef __attribute__((ext_vector_type(16))) float float16v;

__device__ __forceinline__ void gatomic_add(float* p, float v) {
#if defined(__HIP_DEVICE_COMPILE__)
  unsafeAtomicAdd(p, v);  // hw global_atomic_add_f32 on gfx950
#else
  atomicAdd(p, v);
#endif
}

// bf16 truncation: unbiased over symmetric data, 1 VALU op.
__device__ __forceinline__ short f2bf(float f) {
  return (short)(__float_as_uint(f) >> 16);
}

// ---------------------------------------------------------------------------
// Pass 1: sums[c][e] (+counts in col 16) via MFMA segmented sum.
//   A[m][k] = onehot(lab[k]==m), B[k][n] = x[k][e=n] (n<16), 1.0 (n==16).
// Depth-2 register prefetch pipeline: 8 loads in flight per lane, forced
// live across the MFMA so the compiler cannot serialize on vmcnt(0).
// ---------------------------------------------------------------------------
__global__ __launch_bounds__(256) void pass1(const float* __restrict__ input,
                                             const int* __restrict__ target,
                                             float* __restrict__ ws) {
  __shared__ float s_red[4 * 16 * 64];  // [wave][reg][lane], 16 KB
  const int tid = threadIdx.x;
  const int wv = tid >> 6, l = tid & 63;
  const int n = blockIdx.y;
  const int m = l & 31;    // A-row (cluster) / B-col (e or ones)
  const int half = l >> 5; // k-half
  const bool is_e = (m < E_DIM);
  const bool is_one = (m == E_DIM);

  const int base0 = blockIdx.x * PX1 + wv * 256 + half * 8;
  const int* tgt = target + (size_t)n * P_PIX + base0;
  const float* bptr =
      input + ((size_t)n * E_DIM + (is_e ? m : 0)) * P_PIX + base0;

  const short ONE = 0x3F80;  // bf16(1.0)
  float16v acc;
#pragma unroll
  for (int i = 0; i < 16; ++i) acc[i] = 0.f;

  // prime the 2-deep pipeline
  int4 pl0[2], pl1[2];
  float4 pv0[2], pv1[2];
#pragma unroll
  for (int i = 0; i < 2; ++i) {
    const int off = i * 16;
    pl0[i] = *reinterpret_cast<const int4*>(tgt + off);
    pl1[i] = *reinterpret_cast<const int4*>(tgt + off + 4);
    if (is_e) {
      pv0[i] = *reinterpret_cast<const float4*>(bptr + off);
      pv1[i] = *reinterpret_cast<const float4*>(bptr + off + 4);
    }
  }

#pragma unroll
  for (int s = 0; s < STEPS1; ++s) {
    const int slot = s & 1;
    const int4 lab0 = pl0[slot], lab1 = pl1[slot];
    const float4 v0 = pv0[slot], v1 = pv1[slot];
    if (s + 2 < STEPS1) {  // refill the slot two steps ahead
      const int off = (s + 2) * 16;
      pl0[slot] = *reinterpret_cast<const int4*>(tgt + off);
      pl1[slot] = *reinterpret_cast<const int4*>(tgt + off + 4);
      if (is_e) {
        pv0[slot] = *reinterpret_cast<const float4*>(bptr + off);
        pv1[slot] = *reinterpret_cast<const float4*>(bptr + off + 4);
      }
    }
    short8 a;
    a[0] = (lab0.x == m) ? ONE : 0;
    a[1] = (lab0.y == m) ? ONE : 0;
    a[2] = (lab0.z == m) ? ONE : 0;
    a[3] = (lab0.w == m) ? ONE : 0;
    a[4] = (lab1.x == m) ? ONE : 0;
    a[5] = (lab1.y == m) ? ONE : 0;
    a[6] = (lab1.z == m) ? ONE : 0;
    a[7] = (lab1.w == m) ? ONE : 0;
    short8 b;
    if (is_e) {
      b[0] = f2bf(v0.x); b[1] = f2bf(v0.y); b[2] = f2bf(v0.z); b[3] = f2bf(v0.w);
      b[4] = f2bf(v1.x); b[5] = f2bf(v1.y); b[6] = f2bf(v1.z); b[7] = f2bf(v1.w);
    } else {
      const short fill = is_one ? ONE : (short)0;
#pragma unroll
      for (int j = 0; j < 8; ++j) b[j] = fill;
    }
    acc = __builtin_amdgcn_mfma_f32_32x32x16_bf16(a, b, acc, 0, 0, 0);
  }

  // Cross-wave reduce in LDS, then one global atomic per (row,col).
#pragma unroll
  for (int r = 0; r < 16; ++r) s_red[wv * 1024 + r * 64 + l] = acc[r];
  __syncthreads();

  // C/D layout: col = lane&31, row = (reg&3) + 8*(reg>>2) + 4*(lane>>5)
  for (int i = tid; i < C_CL * 17; i += 256) {
    const int row = i / 17;        // cluster
    const int col = i - row * 17;  // e (0..15) or count (16)
    const int lane = col | (((row >> 2) & 1) << 5);
    const int reg = (row & 3) | ((row >> 3) << 2);
    const int idx = reg * 64 + lane;
    const float v = s_red[idx] + s_red[1024 + idx] + s_red[2048 + idx] +
                    s_red[3072 + idx];
    if (col < 16)
      gatomic_add(&ws[WS_SUMS + n * C_CL * E_DIM + row * E_DIM + col], v);
    else
      gatomic_add(&ws[WS_CNT + n * C_CL + row], v);
  }
}

// ---------------------------------------------------------------------------
// Pass 2: Sigma_p h^2_p * invcnt[lab_p]. One float4-pixel per thread; all 16
// e-loads issued upfront as one independent bundle (max MLP), then consumed.
// ---------------------------------------------------------------------------
__global__ __launch_bounds__(256) void pass2(const float* __restrict__ input,
                                             const int* __restrict__ target,
                                             float* __restrict__ ws) {
  __shared__ float s_mean[C_CL * 17];  // stride 17: bank bijective in c
  __shared__ float s_invc[C_CL];
  __shared__ float s_red[256];
  const int tid = threadIdx.x;
  const int n = blockIdx.y;
  for (int i = tid; i < C_CL * E_DIM; i += 256) {
    const int c = i >> 4, e = i & 15;
    s_mean[c * 17 + e] =
        ws[WS_SUMS + n * C_CL * E_DIM + i] / ws[WS_CNT + n * C_CL + c];
  }
  if (tid < C_CL) s_invc[tid] = 1.0f / ws[WS_CNT + n * C_CL + tid];
  __syncthreads();

  const int p = blockIdx.x * PX2 + tid * 4;
  const float* inp = input + (size_t)n * E_DIM * P_PIX + p;
  const int4 lab = *reinterpret_cast<const int4*>(target + (size_t)n * P_PIX + p);

  float4 v[E_DIM];
#pragma unroll
  for (int e = 0; e < E_DIM; ++e)
    v[e] = *reinterpret_cast<const float4*>(inp + (size_t)e * P_PIX);

  const float* mx = s_mean + lab.x * 17;
  const float* my = s_mean + lab.y * 17;
  const float* mz = s_mean + lab.z * 17;
  const float* mw = s_mean + lab.w * 17;
  float ax = 0.f, ay = 0.f, az = 0.f, aw = 0.f;
#pragma unroll
  for (int e = 0; e < E_DIM; ++e) {
    const float dx = v[e].x - mx[e];
    const float dy = v[e].y - my[e];
    const float dz = v[e].z - mz[e];
    const float dw = v[e].w - mw[e];
    ax += dx * dx; ay += dy * dy; az += dz * dz; aw += dw * dw;
  }
  float acc = 0.f, d, h;
  d = sqrtf(fmaxf(ax, EPS_F)); h = fmaxf(d - DELTA_VAR, 0.f);
  acc += h * h * s_invc[lab.x];
  d = sqrtf(fmaxf(ay, EPS_F)); h = fmaxf(d - DELTA_VAR, 0.f);
  acc += h * h * s_invc[lab.y];
  d = sqrtf(fmaxf(az, EPS_F)); h = fmaxf(d - DELTA_VAR, 0.f);
  acc += h * h * s_invc[lab.z];
  d = sqrtf(fmaxf(aw, EPS_F)); h = fmaxf(d - DELTA_VAR, 0.f);
  acc += h * h * s_invc[lab.w];

  s_red[tid] = acc;
  __syncthreads();
  for (int s2 = 128; s2 > 0; s2 >>= 1) {
    if (tid < s2) s_red[tid] += s_red[tid + s2];
    __syncthreads();
  }
  if (tid == 0) gatomic_add(&ws[WS_VAR + n], s_red[0]);
}

// ---------------------------------------------------------------------------
// Finalize: variance + pairwise distance + regularizer -> scalar.
// ---------------------------------------------------------------------------
__global__ __launch_bounds__(256) void finalize(const float* __restrict__ ws,
                                                float* __restrict__ out) {
  __shared__ float s_mean[N_IMG * C_CL * E_DIM];  // 2048 floats
  __shared__ float red[256];
  const int tid = threadIdx.x;
  for (int i = tid; i < N_IMG * C_CL * E_DIM; i += 256) {
    s_mean[i] = ws[WS_SUMS + i] / ws[WS_CNT + (i >> 4)];
  }
  __syncthreads();

  float acc = 0.f;
  for (int i = tid; i < N_IMG; i += 256) acc += ws[WS_VAR + i] * (1.0f / C_CL);
  for (int i = tid; i < N_IMG * C_CL; i += 256) {
    float nrm2 = 0.f;
    const float* m = s_mean + i * E_DIM;
#pragma unroll
    for (int e = 0; e < E_DIM; ++e) nrm2 += m[e] * m[e];
    acc += GAMMA_W * sqrtf(fmaxf(nrm2, EPS_F)) * (1.0f / C_CL);
  }
  for (int t = tid; t < N_IMG * C_CL * C_CL; t += 256) {
    const int n = t / (C_CL * C_CL);
    const int r = t - n * C_CL * C_CL;
    const int a = r >> 5, b = r & 31;
    if (a != b) {
      const float* ma = s_mean + (n * C_CL + a) * E_DIM;
      const float* mb = s_mean + (n * C_CL + b) * E_DIM;
      float d2 = 0.f;
#pragma unroll
      for (int e = 0; e < E_DIM; ++e) {
        const float df = ma[e] - mb[e];
        d2 += df * df;
      }
      const float dist = sqrtf(fmaxf(d2, EPS_F));
      const float hd = fmaxf(2.f * DELTA_DIST - dist, 0.f);
      acc += hd * hd * (1.0f / (C_CL * (C_CL - 1)));
    }
  }

  red[tid] = acc;
  __syncthreads();
  for (int s = 128; s > 0; s >>= 1) {
    if (tid < s) red[tid] += red[tid + s];
    __syncthreads();
  }
  if (tid == 0) out[0] = red[0] * (1.0f / N_IMG);
}

extern "C" void kernel_launch(void* const* d_in, const int* in_sizes, int n_in,
                              void* d_out, int out_size, void* d_ws,
                              size_t ws_size, hipStream_t stream) {
  const float* input = (const float*)d_in[0];
  const int* target = (const int*)d_in[1];
  float* ws = (float*)d_ws;
  float* out = (float*)d_out;

  hipMemsetAsync(ws, 0, WS_TOTAL * sizeof(float), stream);
  pass1<<<dim3(BX1, N_IMG), 256, 0, stream>>>(input, target, ws);
  pass2<<<dim3(BX2, N_IMG), 256, 0, stream>>>(input, target, ws);
  finalize<<<1, 256, 0, stream>>>(ws, out);
}

// Round 5
// 308.133 us; speedup vs baseline: 1.1142x; 1.1142x over previous
//
#include <hip/hip_runtime.h>

// Problem constants (fixed by setup_inputs)
#define N_IMG 4
#define E_DIM 16
#define H_DIM 768
#define W_DIM 768
#define P_PIX (H_DIM * W_DIM)   // 589824 pixels per image
#define C_CL 32

#define DELTA_VAR 0.5f
#define DELTA_DIST 2.0f
#define GAMMA_W 0.001f
#define EPS_F 1e-12f

// Workspace layout (floats):
//   [0,    2048): sums   [N][C][E]
//   [2048, 2176): counts [N][C]
//   [2176, 2180): varsum [N]
#define WS_SUMS 0
#define WS_CNT 2048
#define WS_VAR 2176
#define WS_TOTAL 2180

// pass1 tiling: 1536 px per block, 384 chunks/image, wave-contiguous staging.
#define TP1 1536
#define CH1 (P_PIX / TP1)    // 384
#define TSTRIDE 1540         // tile row stride in shorts (3080 B; bank start 2*row)
#define STEPS1 (TP1 / 4 / 16)  // 24 MFMA steps per wave (384 px per wave)

// pass2: 1024 px per block
#define PX2 1024
#define BX2 (P_PIX / PX2)    // 576

typedef __attribute__((ext_vector_type(8))) short short8;
typedef __attribute__((ext_vector_type(16))) float float16v;

__device__ __forceinline__ void gatomic_add(float* p, float v) {
#if defined(__HIP_DEVICE_COMPILE__)
  unsafeAtomicAdd(p, v);  // hw global_atomic_add_f32 on gfx950
#else
  atomicAdd(p, v);
#endif
}

// bf16 truncation: unbiased over symmetric data, 1 VALU op.
__device__ __forceinline__ short f2bf(float f) {
  return (short)(__float_as_uint(f) >> 16);
}

// ---------------------------------------------------------------------------
// Pass 1: sums[c][e] (+counts in col 16) via MFMA segmented sum, fed from an
// LDS tile staged with WAVE-CONTIGUOUS global reads (channel-spread), instead
// of lane-per-row strided reads (channel camping -> 620 GB/s in R3/R4).
//   A[m][k] = onehot(lab[k]==m)  (from LDS labels, broadcast reads)
//   B[k][n] = tile[n][k]: n<16 data rows (bf16), n==16 ones row (counts).
// ---------------------------------------------------------------------------
__global__ __launch_bounds__(256) void pass1(const float* __restrict__ input,
                                             const int* __restrict__ target,
                                             float* __restrict__ ws) {
  __shared__ int s_lab[TP1];              // 6144 B
  __shared__ short s_tile[17 * TSTRIDE];  // 52360 B (rows 0..15 data, 16 ones)
  const int tid = threadIdx.x;
  const int wv = tid >> 6, l = tid & 63;
  const int n = blockIdx.y;
  const int base = blockIdx.x * TP1;
  const int* tgt = target + (size_t)n * P_PIX + base;

  // ---- stage labels (coalesced int4) ----
  for (int i = tid; i < TP1 / 4; i += 256) {
    *reinterpret_cast<int4*>(&s_lab[i * 4]) =
        *reinterpret_cast<const int4*>(tgt + i * 4);
  }
  // ---- ones row (counts column) ----
  for (int i = tid; i < TP1; i += 256)
    s_tile[16 * TSTRIDE + i] = (short)0x3F80;  // bf16(1.0)
  // ---- stage data rows: wave wv handles rows 4wv..4wv+3, contiguous reads ----
#pragma unroll
  for (int r = 0; r < 4; ++r) {
    const int row = (wv << 2) + r;
    const float* src = input + ((size_t)n * E_DIM + row) * P_PIX + base;
    float4 v[6];
#pragma unroll
    for (int it = 0; it < 6; ++it)  // 6 independent 1KB wave-bursts in flight
      v[it] = *reinterpret_cast<const float4*>(src + it * 256 + l * 4);
#pragma unroll
    for (int it = 0; it < 6; ++it) {
      short4 b4;
      b4.x = f2bf(v[it].x);
      b4.y = f2bf(v[it].y);
      b4.z = f2bf(v[it].z);
      b4.w = f2bf(v[it].w);
      *reinterpret_cast<short4*>(&s_tile[row * TSTRIDE + it * 256 + l * 4]) = b4;
    }
  }
  __syncthreads();

  // ---- MFMA over this wave's k-range [wv*384, wv*384+384) ----
  const int m = l & 31;     // A-row (cluster) / B-col (e or ones)
  const int half = l >> 5;  // k-half
  const int brow = (m < 17) ? m : 16;  // clamp: cols 17..31 harmless, no OOB
  const short* bbase = &s_tile[brow * TSTRIDE + half * 8];
  const int k0w = wv * (TP1 / 4);
  const short ONE = 0x3F80;

  float16v acc;
#pragma unroll
  for (int i = 0; i < 16; ++i) acc[i] = 0.f;

#pragma unroll
  for (int s = 0; s < STEPS1; ++s) {
    const int k0 = k0w + s * 16;
    const int4 la = *reinterpret_cast<const int4*>(&s_lab[k0 + half * 8]);
    const int4 lb = *reinterpret_cast<const int4*>(&s_lab[k0 + half * 8 + 4]);
    const short4 b0 = *reinterpret_cast<const short4*>(bbase + s * 16);
    const short4 b1 = *reinterpret_cast<const short4*>(bbase + s * 16 + 4);
    short8 a, b;
    a[0] = (la.x == m) ? ONE : 0;
    a[1] = (la.y == m) ? ONE : 0;
    a[2] = (la.z == m) ? ONE : 0;
    a[3] = (la.w == m) ? ONE : 0;
    a[4] = (lb.x == m) ? ONE : 0;
    a[5] = (lb.y == m) ? ONE : 0;
    a[6] = (lb.z == m) ? ONE : 0;
    a[7] = (lb.w == m) ? ONE : 0;
    b[0] = b0.x; b[1] = b0.y; b[2] = b0.z; b[3] = b0.w;
    b[4] = b1.x; b[5] = b1.y; b[6] = b1.z; b[7] = b1.w;
    acc = __builtin_amdgcn_mfma_f32_32x32x16_bf16(a, b, acc, 0, 0, 0);
  }

  // ---- cross-wave reduce (reuse tile LDS as [wave][reg][lane]) ----
  __syncthreads();  // all tile reads complete before aliasing
  float* s_red = reinterpret_cast<float*>(s_tile);
#pragma unroll
  for (int r = 0; r < 16; ++r) s_red[wv * 1024 + r * 64 + l] = acc[r];
  __syncthreads();

  // C/D layout (verified): col = lane&31, row = (reg&3) + 8*(reg>>2) + 4*(lane>>5)
  for (int i = tid; i < C_CL * 17; i += 256) {
    const int row = i / 17;        // cluster
    const int col = i - row * 17;  // e (0..15) or count (16)
    const int lane = col | (((row >> 2) & 1) << 5);
    const int reg = (row & 3) | ((row >> 3) << 2);
    const int idx = reg * 64 + lane;
    const float v = s_red[idx] + s_red[1024 + idx] + s_red[2048 + idx] +
                    s_red[3072 + idx];
    if (col < 16)
      gatomic_add(&ws[WS_SUMS + n * C_CL * E_DIM + row * E_DIM + col], v);
    else
      gatomic_add(&ws[WS_CNT + n * C_CL + row], v);
  }
}

// ---------------------------------------------------------------------------
// Pass 2: Sigma_p h^2_p * invcnt[lab_p]. One float4-pixel per thread; all 16
// e-loads issued upfront (each wave-inst is 1KB contiguous -> channel-spread).
// ---------------------------------------------------------------------------
__global__ __launch_bounds__(256) void pass2(const float* __restrict__ input,
                                             const int* __restrict__ target,
                                             float* __restrict__ ws) {
  __shared__ float s_mean[C_CL * 17];  // stride 17: bank bijective in c
  __shared__ float s_invc[C_CL];
  __shared__ float s_red[256];
  const int tid = threadIdx.x;
  const int n = blockIdx.y;
  for (int i = tid; i < C_CL * E_DIM; i += 256) {
    const int c = i >> 4, e = i & 15;
    s_mean[c * 17 + e] =
        ws[WS_SUMS + n * C_CL * E_DIM + i] / ws[WS_CNT + n * C_CL + c];
  }
  if (tid < C_CL) s_invc[tid] = 1.0f / ws[WS_CNT + n * C_CL + tid];
  __syncthreads();

  const int p = blockIdx.x * PX2 + tid * 4;
  const float* inp = input + (size_t)n * E_DIM * P_PIX + p;
  const int4 lab = *reinterpret_cast<const int4*>(target + (size_t)n * P_PIX + p);

  float4 v[E_DIM];
#pragma unroll
  for (int e = 0; e < E_DIM; ++e)
    v[e] = *reinterpret_cast<const float4*>(inp + (size_t)e * P_PIX);

  const float* mx = s_mean + lab.x * 17;
  const float* my = s_mean + lab.y * 17;
  const float* mz = s_mean + lab.z * 17;
  const float* mw = s_mean + lab.w * 17;
  float ax = 0.f, ay = 0.f, az = 0.f, aw = 0.f;
#pragma unroll
  for (int e = 0; e < E_DIM; ++e) {
    const float dx = v[e].x - mx[e];
    const float dy = v[e].y - my[e];
    const float dz = v[e].z - mz[e];
    const float dw = v[e].w - mw[e];
    ax += dx * dx; ay += dy * dy; az += dz * dz; aw += dw * dw;
  }
  float acc = 0.f, d, h;
  d = sqrtf(fmaxf(ax, EPS_F)); h = fmaxf(d - DELTA_VAR, 0.f);
  acc += h * h * s_invc[lab.x];
  d = sqrtf(fmaxf(ay, EPS_F)); h = fmaxf(d - DELTA_VAR, 0.f);
  acc += h * h * s_invc[lab.y];
  d = sqrtf(fmaxf(az, EPS_F)); h = fmaxf(d - DELTA_VAR, 0.f);
  acc += h * h * s_invc[lab.z];
  d = sqrtf(fmaxf(aw, EPS_F)); h = fmaxf(d - DELTA_VAR, 0.f);
  acc += h * h * s_invc[lab.w];

  s_red[tid] = acc;
  __syncthreads();
  for (int s2 = 128; s2 > 0; s2 >>= 1) {
    if (tid < s2) s_red[tid] += s_red[tid + s2];
    __syncthreads();
  }
  if (tid == 0) gatomic_add(&ws[WS_VAR + n], s_red[0]);
}

// ---------------------------------------------------------------------------
// Finalize: variance + pairwise distance + regularizer -> scalar.
// ---------------------------------------------------------------------------
__global__ __launch_bounds__(256) void finalize(const float* __restrict__ ws,
                                                float* __restrict__ out) {
  __shared__ float s_mean[N_IMG * C_CL * E_DIM];  // 2048 floats
  __shared__ float red[256];
  const int tid = threadIdx.x;
  for (int i = tid; i < N_IMG * C_CL * E_DIM; i += 256) {
    s_mean[i] = ws[WS_SUMS + i] / ws[WS_CNT + (i >> 4)];
  }
  __syncthreads();

  float acc = 0.f;
  for (int i = tid; i < N_IMG; i += 256) acc += ws[WS_VAR + i] * (1.0f / C_CL);
  for (int i = tid; i < N_IMG * C_CL; i += 256) {
    float nrm2 = 0.f;
    const float* m = s_mean + i * E_DIM;
#pragma unroll
    for (int e = 0; e < E_DIM; ++e) nrm2 += m[e] * m[e];
    acc += GAMMA_W * sqrtf(fmaxf(nrm2, EPS_F)) * (1.0f / C_CL);
  }
  for (int t = tid; t < N_IMG * C_CL * C_CL; t += 256) {
    const int n = t / (C_CL * C_CL);
    const int r = t - n * C_CL * C_CL;
    const int a = r >> 5, b = r & 31;
    if (a != b) {
      const float* ma = s_mean + (n * C_CL + a) * E_DIM;
      const float* mb = s_mean + (n * C_CL + b) * E_DIM;
      float d2 = 0.f;
#pragma unroll
      for (int e = 0; e < E_DIM; ++e) {
        const float df = ma[e] - mb[e];
        d2 += df * df;
      }
      const float dist = sqrtf(fmaxf(d2, EPS_F));
      const float hd = fmaxf(2.f * DELTA_DIST - dist, 0.f);
      acc += hd * hd * (1.0f / (C_CL * (C_CL - 1)));
    }
  }

  red[tid] = acc;
  __syncthreads();
  for (int s = 128; s > 0; s >>= 1) {
    if (tid < s) red[tid] += red[tid + s];
    __syncthreads();
  }
  if (tid == 0) out[0] = red[0] * (1.0f / N_IMG);
}

extern "C" void kernel_launch(void* const* d_in, const int* in_sizes, int n_in,
                              void* d_out, int out_size, void* d_ws,
                              size_t ws_size, hipStream_t stream) {
  const float* input = (const float*)d_in[0];
  const int* target = (const int*)d_in[1];
  float* ws = (float*)d_ws;
  float* out = (float*)d_out;

  hipMemsetAsync(ws, 0, WS_TOTAL * sizeof(float), stream);
  pass1<<<dim3(CH1, N_IMG), 256, 0, stream>>>(input, target, ws);
  pass2<<<dim3(BX2, N_IMG), 256, 0, stream>>>(input, target, ws);
  finalize<<<1, 256, 0, stream>>>(ws, out);
}

// Round 6
// 289.108 us; speedup vs baseline: 1.1876x; 1.0658x over previous
//
#include <hip/hip_runtime.h>

// Problem constants (fixed by setup_inputs)
#define N_IMG 4
#define E_DIM 16
#define H_DIM 768
#define W_DIM 768
#define P_PIX (H_DIM * W_DIM)   // 589824 pixels per image
#define C_CL 32

#define DELTA_VAR 0.5f
#define DELTA_DIST 2.0f
#define GAMMA_W 0.001f
#define EPS_F 1e-12f

// pass1: 144 blocks/image, 4096 px/block, 1024 px/wave, 64 MFMA steps.
#define B1 144
#define PXB1 (P_PIX / B1)    // 4096
#define PXW1 (PXB1 / 4)      // 1024
#define STEPS1 (PXW1 / 16)   // 64

// pass2: 1024 px per block
#define PX2 1024
#define BX2 (P_PIX / PX2)    // 576

// Workspace layout (floats). All regions fully written before read -> no memset.
//   partials1: [N*B1][544]   (544 = 32 clusters x (16 sums + 1 count))
//   sums:      [N][544]
//   varpart:   [N*BX2]
#define WS_PART1 0
#define WS_SUMS (N_IMG * B1 * 544)
#define WS_VARP (WS_SUMS + N_IMG * 544)

typedef __attribute__((ext_vector_type(8))) short short8;
typedef __attribute__((ext_vector_type(16))) float float16v;

// bf16 truncation: unbiased over symmetric data, 1 VALU op.
__device__ __forceinline__ short f2bf(float f) {
  return (short)(__float_as_uint(f) >> 16);
}

// ---------------------------------------------------------------------------
// Pass 1: per-block partial sums[c][e] (+count col 16) via MFMA segmented sum.
//   A[m][k] = onehot(lab[k]==m), B[k][n] = x[k][e=n] (n<16), 1.0 (n==16).
// NO global atomics: each block stores a private 544-float partial (plain,
// coalesced). Cross-block reduction happens in reduce1.
// ---------------------------------------------------------------------------
__global__ __launch_bounds__(256) void pass1(const float* __restrict__ input,
                                             const int* __restrict__ target,
                                             float* __restrict__ ws) {
  __shared__ float s_red[4 * 16 * 64];  // [wave][reg][lane], 16 KB
  const int tid = threadIdx.x;
  const int wv = tid >> 6, l = tid & 63;
  const int n = blockIdx.y;
  const int m = l & 31;    // A-row (cluster) / B-col (e or ones)
  const int half = l >> 5; // k-half
  const bool is_e = (m < E_DIM);
  const bool is_one = (m == E_DIM);

  const int base0 = blockIdx.x * PXB1 + wv * PXW1 + half * 8;
  const int* tgt = target + (size_t)n * P_PIX + base0;
  const float* bptr =
      input + ((size_t)n * E_DIM + (is_e ? m : 0)) * P_PIX + base0;

  const short ONE = 0x3F80;  // bf16(1.0)
  float16v acc;
#pragma unroll
  for (int i = 0; i < 16; ++i) acc[i] = 0.f;

  for (int s = 0; s < STEPS1; ++s) {
    const int off = s * 16;
    const int4 lab0 = *reinterpret_cast<const int4*>(tgt + off);
    const int4 lab1 = *reinterpret_cast<const int4*>(tgt + off + 4);
    short8 a;
    a[0] = (lab0.x == m) ? ONE : 0;
    a[1] = (lab0.y == m) ? ONE : 0;
    a[2] = (lab0.z == m) ? ONE : 0;
    a[3] = (lab0.w == m) ? ONE : 0;
    a[4] = (lab1.x == m) ? ONE : 0;
    a[5] = (lab1.y == m) ? ONE : 0;
    a[6] = (lab1.z == m) ? ONE : 0;
    a[7] = (lab1.w == m) ? ONE : 0;
    short8 b;
    if (is_e) {
      const float4 v0 = *reinterpret_cast<const float4*>(bptr + off);
      const float4 v1 = *reinterpret_cast<const float4*>(bptr + off + 4);
      b[0] = f2bf(v0.x); b[1] = f2bf(v0.y); b[2] = f2bf(v0.z); b[3] = f2bf(v0.w);
      b[4] = f2bf(v1.x); b[5] = f2bf(v1.y); b[6] = f2bf(v1.z); b[7] = f2bf(v1.w);
    } else {
      const short fill = is_one ? ONE : (short)0;
#pragma unroll
      for (int j = 0; j < 8; ++j) b[j] = fill;
    }
    acc = __builtin_amdgcn_mfma_f32_32x32x16_bf16(a, b, acc, 0, 0, 0);
  }

  // Cross-wave reduce in LDS, then one PLAIN coalesced store per entry.
#pragma unroll
  for (int r = 0; r < 16; ++r) s_red[wv * 1024 + r * 64 + l] = acc[r];
  __syncthreads();

  // C/D layout (verified): col = lane&31, row = (reg&3) + 8*(reg>>2) + 4*(lane>>5)
  float* part = ws + WS_PART1 + ((size_t)(n * B1 + blockIdx.x)) * 544;
  for (int i = tid; i < C_CL * 17; i += 256) {
    const int row = i / 17;        // cluster
    const int col = i - row * 17;  // e (0..15) or count (16)
    const int lane = col | (((row >> 2) & 1) << 5);
    const int reg = (row & 3) | ((row >> 3) << 2);
    const int idx = reg * 64 + lane;
    part[i] = s_red[idx] + s_red[1024 + idx] + s_red[2048 + idx] +
              s_red[3072 + idx];
  }
}

// ---------------------------------------------------------------------------
// Reduce1: sums[n][i] = Sigma_b partials[n][b][i]. One block per image.
// ---------------------------------------------------------------------------
__global__ __launch_bounds__(256) void reduce1(float* __restrict__ ws) {
  const int n = blockIdx.x;
  const int tid = threadIdx.x;
  const float* part = ws + WS_PART1 + (size_t)n * B1 * 544;
  float* sums = ws + WS_SUMS + n * 544;
  for (int i = tid; i < 544; i += 256) {
    float acc = 0.f;
#pragma unroll 8
    for (int b = 0; b < B1; ++b) acc += part[(size_t)b * 544 + i];
    sums[i] = acc;
  }
}

// ---------------------------------------------------------------------------
// Pass 2: Sigma_p h^2_p * invcnt[lab_p]. One float4-pixel per thread; all 16
// e-loads issued upfront. Per-block partial -> PLAIN store (no atomics).
// ---------------------------------------------------------------------------
__global__ __launch_bounds__(256) void pass2(const float* __restrict__ input,
                                             const int* __restrict__ target,
                                             float* __restrict__ ws) {
  __shared__ float s_mean[C_CL * 17];  // stride 17: bank bijective in c
  __shared__ float s_invc[C_CL];
  __shared__ float s_red[256];
  const int tid = threadIdx.x;
  const int n = blockIdx.y;
  const float* sums = ws + WS_SUMS + n * 544;
  for (int i = tid; i < C_CL * E_DIM; i += 256) {
    const int c = i >> 4, e = i & 15;
    s_mean[c * 17 + e] = sums[c * 17 + e] / sums[c * 17 + 16];
  }
  if (tid < C_CL) s_invc[tid] = 1.0f / sums[tid * 17 + 16];
  __syncthreads();

  const int p = blockIdx.x * PX2 + tid * 4;
  const float* inp = input + (size_t)n * E_DIM * P_PIX + p;
  const int4 lab = *reinterpret_cast<const int4*>(target + (size_t)n * P_PIX + p);

  float4 v[E_DIM];
#pragma unroll
  for (int e = 0; e < E_DIM; ++e)
    v[e] = *reinterpret_cast<const float4*>(inp + (size_t)e * P_PIX);

  const float* mx = s_mean + lab.x * 17;
  const float* my = s_mean + lab.y * 17;
  const float* mz = s_mean + lab.z * 17;
  const float* mw = s_mean + lab.w * 17;
  float ax = 0.f, ay = 0.f, az = 0.f, aw = 0.f;
#pragma unroll
  for (int e = 0; e < E_DIM; ++e) {
    const float dx = v[e].x - mx[e];
    const float dy = v[e].y - my[e];
    const float dz = v[e].z - mz[e];
    const float dw = v[e].w - mw[e];
    ax += dx * dx; ay += dy * dy; az += dz * dz; aw += dw * dw;
  }
  float acc = 0.f, d, h;
  d = sqrtf(fmaxf(ax, EPS_F)); h = fmaxf(d - DELTA_VAR, 0.f);
  acc += h * h * s_invc[lab.x];
  d = sqrtf(fmaxf(ay, EPS_F)); h = fmaxf(d - DELTA_VAR, 0.f);
  acc += h * h * s_invc[lab.y];
  d = sqrtf(fmaxf(az, EPS_F)); h = fmaxf(d - DELTA_VAR, 0.f);
  acc += h * h * s_invc[lab.z];
  d = sqrtf(fmaxf(aw, EPS_F)); h = fmaxf(d - DELTA_VAR, 0.f);
  acc += h * h * s_invc[lab.w];

  s_red[tid] = acc;
  __syncthreads();
  for (int s2 = 128; s2 > 0; s2 >>= 1) {
    if (tid < s2) s_red[tid] += s_red[tid + s2];
    __syncthreads();
  }
  if (tid == 0) ws[WS_VARP + n * BX2 + blockIdx.x] = s_red[0];
}

// ---------------------------------------------------------------------------
// Finalize: variance partials + pairwise distance + regularizer -> scalar.
// ---------------------------------------------------------------------------
__global__ __launch_bounds__(256) void finalize(const float* __restrict__ ws,
                                                float* __restrict__ out) {
  __shared__ float s_mean[N_IMG * C_CL * E_DIM];  // 2048 floats
  __shared__ float red[256];
  const int tid = threadIdx.x;
  for (int i = tid; i < N_IMG * C_CL * E_DIM; i += 256) {
    const int n = i >> 9, rem = i & 511;
    const int c = rem >> 4, e = rem & 15;
    s_mean[i] = ws[WS_SUMS + n * 544 + c * 17 + e] /
                ws[WS_SUMS + n * 544 + c * 17 + 16];
  }
  __syncthreads();

  float acc = 0.f;
  // variance partials (2304 plain floats)
  for (int i = tid; i < N_IMG * BX2; i += 256)
    acc += ws[WS_VARP + i] * (1.0f / C_CL);
  // regularizer over 128 (n,c) cells
  for (int i = tid; i < N_IMG * C_CL; i += 256) {
    float nrm2 = 0.f;
    const float* m = s_mean + i * E_DIM;
#pragma unroll
    for (int e = 0; e < E_DIM; ++e) nrm2 += m[e] * m[e];
    acc += GAMMA_W * sqrtf(fmaxf(nrm2, EPS_F)) * (1.0f / C_CL);
  }
  // pairwise distance term: 4 * 32 * 32 cells
  for (int t = tid; t < N_IMG * C_CL * C_CL; t += 256) {
    const int n = t / (C_CL * C_CL);
    const int r = t - n * C_CL * C_CL;
    const int a = r >> 5, b = r & 31;
    if (a != b) {
      const float* ma = s_mean + (n * C_CL + a) * E_DIM;
      const float* mb = s_mean + (n * C_CL + b) * E_DIM;
      float d2 = 0.f;
#pragma unroll
      for (int e = 0; e < E_DIM; ++e) {
        const float df = ma[e] - mb[e];
        d2 += df * df;
      }
      const float dist = sqrtf(fmaxf(d2, EPS_F));
      const float hd = fmaxf(2.f * DELTA_DIST - dist, 0.f);
      acc += hd * hd * (1.0f / (C_CL * (C_CL - 1)));
    }
  }

  red[tid] = acc;
  __syncthreads();
  for (int s = 128; s > 0; s >>= 1) {
    if (tid < s) red[tid] += red[tid + s];
    __syncthreads();
  }
  if (tid == 0) out[0] = red[0] * (1.0f / N_IMG);
}

extern "C" void kernel_launch(void* const* d_in, const int* in_sizes, int n_in,
                              void* d_out, int out_size, void* d_ws,
                              size_t ws_size, hipStream_t stream) {
  const float* input = (const float*)d_in[0];
  const int* target = (const int*)d_in[1];
  float* ws = (float*)d_ws;
  float* out = (float*)d_out;

  pass1<<<dim3(B1, N_IMG), 256, 0, stream>>>(input, target, ws);
  reduce1<<<N_IMG, 256, 0, stream>>>(ws);
  pass2<<<dim3(BX2, N_IMG), 256, 0, stream>>>(input, target, ws);
  finalize<<<1, 256, 0, stream>>>(ws, out);
}